// Round 1
// baseline (309.917 us; speedup 1.0000x reference)
//
#include <hip/hip_runtime.h>
#include <hip/hip_bf16.h>

#define BB 4
#define TT 2048
#define CC 1024
#define HH 16
#define DD 64
#define PSTR 72   // Ps row stride in u16 (144B = 9*16B: aligned, 2-way-free banks)

typedef unsigned short u16;
typedef __attribute__((ext_vector_type(8))) short bf16x8;
typedef __attribute__((ext_vector_type(4))) float f32x4;
typedef __attribute__((ext_vector_type(16))) float f32x16;

__device__ __forceinline__ float bf2f(u16 v) {
    union { unsigned u; float f; } c; c.u = ((unsigned)v) << 16; return c.f;
}
__device__ __forceinline__ u16 f2bf(float f) {
    union { float f; unsigned u; } c; c.f = f;
    unsigned u = c.u + 0x7fffu + ((c.u >> 16) & 1u);
    return (u16)(u >> 16);
}
__device__ __forceinline__ float fast_exp2(float x) {
    float r;
    asm volatile("v_exp_f32 %0, %1\n\ts_nop 1" : "=v"(r) : "v"(x));
    return r;
}
__device__ __forceinline__ unsigned pack_bf16(unsigned b0, unsigned b1) {
    unsigned d;
    asm("v_perm_b32 %0, %1, %2, %3" : "=v"(d) : "v"(b1), "v"(b0), "v"(0x07060302u));
    return d;
}
__device__ __forceinline__ uint2 pack4(float v0, float v1, float v2, float v3) {
    uint2 pk;
    pk.x = pack_bf16(__float_as_uint(v0) + 0x8000u, __float_as_uint(v1) + 0x8000u);
    pk.y = pack_bf16(__float_as_uint(v2) + 0x8000u, __float_as_uint(v3) + 0x8000u);
    return pk;
}
__device__ __forceinline__ void gload16(const u16* g, u16* l) {
    __builtin_amdgcn_global_load_lds(
        (const __attribute__((address_space(1))) void*)g,
        (__attribute__((address_space(3))) void*)l, 16, 0, 0);
}

// inline dtype detect (256-thread blocks): even u16s of x; bf16 ~248 hits, fp32 ~15
__device__ __forceinline__ int detect_bf16(const u16* __restrict__ xprobe, int* sh) {
    const int t = threadIdx.x;
    u16 hh = xprobe[2 * t];
    int e = (hh >> 7) & 0xFF;
    unsigned long long m = __ballot(e >= 118 && e <= 132);
    if ((t & 63) == 0) sh[t >> 6] = __popcll(m);
    __syncthreads();
    return (sh[0] + sh[1] + sh[2] + sh[3]) >= 128;
}
// 512-thread variant for the new proj kernel
__device__ __forceinline__ int detect_bf16_512(const u16* __restrict__ xprobe, int* sh) {
    const int t = threadIdx.x;
    u16 hh = xprobe[2 * t];
    int e = (hh >> 7) & 0xFF;
    unsigned long long m = __ballot(e >= 118 && e <= 132);
    if ((t & 63) == 0) sh[t >> 6] = __popcll(m);
    __syncthreads();
    int s = 0;
#pragma unroll
    for (int w = 0; w < 8; w++) s += sh[w];
    return s >= 256;
}

// ---- fused canonicalize (detect inlined) ----
struct CastArgs {
    const void* src[9];
    u16* dst[9];
    int blk_start[10];
    int n[9];
};
__global__ __launch_bounds__(256) void cast_all(CastArgs a, const u16* __restrict__ xprobe) {
    __shared__ int sh[4];
    const int isbf = detect_bf16(xprobe, sh);
    int b = blockIdx.x;
    int s = 0;
    while (s < 8 && b >= a.blk_start[s + 1]) s++;
    int i0 = (b - a.blk_start[s]) * 2048 + threadIdx.x * 8;
    if (i0 + 8 > a.n[s]) return;
    if (isbf) {
        *(uint4*)&a.dst[s][i0] = *(const uint4*)&((const u16*)a.src[s])[i0];
    } else {
        const float* sp = (const float*)a.src[s];
        u16 tmp[8];
#pragma unroll
        for (int j = 0; j < 8; j++) tmp[j] = f2bf(sp[i0 + j]);
        *(uint4*)&a.dst[s][i0] = *(uint4*)tmp;
    }
}

// ============================================================================
// GEMM core v2: counted-vmcnt pipelined, BK=32, 4-deep LDS ring, 8 waves.
//   MI=4: BM=256 (qkv)   MI=2: BM=128 (proj)    BN=256 always.
// LDS cell layout (16B cells, per region of R rows x 4 k-chunks):
//   cell(r,c) at i = ((r ^ 2c ^ (r>>3)) & 7) + 8*((r>>3) + (R/8)*c)
//   -> bank group i&7 varies for lane offsets 8/16/24/32 => conflict-free reads.
// Staging: gload_lds dest is LINEAR (wave*cells + j*64 + lane); global source
// address carries the inverse permutation (both-sides-or-neither rule).
// Per K-tile: 2 phases x {ds_read frags | stage tile t+2 | vmcnt(N) | barrier |
// lgkmcnt(0) | setprio(1) 8xMFMA setprio(0) | barrier}.  vmcnt never 0 in loop.
// ============================================================================
template<int MI>
__device__ __forceinline__ void gemm8p(
    const u16* __restrict__ X, const u16* __restrict__ W,
    u16* L, f32x16 (&acc)[MI][2],
    int m0, int n0, int wave, int lane)
{
    constexpr int RA     = MI * 64;        // A rows per tile: 256 or 128
    constexpr int AU16   = RA * 32;        // A u16 per buf: 8192 or 4096
    constexpr int BUFSTR = AU16 + 8192;    // + B (256 rows x 32k)
    constexpr int NTILE  = CC / 32;        // 32 K-tiles

    const int l32 = lane & 31;
    const int hv  = lane >> 5;
    const int wm  = (wave >> 2) * (MI * 32);
    const int wn  = (wave & 3) * 64;

    // ---- LDS read offsets (u16), fixed across tiles ----
    int offA[MI][2], offB[2][2];
#pragma unroll
    for (int mi = 0; mi < MI; mi++)
#pragma unroll
        for (int ks = 0; ks < 2; ks++) {
            const int r  = wm + mi * 32 + l32;
            const int c  = ks * 2 + hv;
            const int rb = r >> 3;
            const int lo = (r & 7) ^ ((2 * c) & 7) ^ (rb & 7);
            offA[mi][ks] = (lo + 8 * (rb + (RA / 8) * c)) * 8;
        }
#pragma unroll
    for (int nj = 0; nj < 2; nj++)
#pragma unroll
        for (int ks = 0; ks < 2; ks++) {
            const int r  = wn + nj * 32 + l32;
            const int c  = ks * 2 + hv;
            const int rb = r >> 3;
            const int lo = (r & 7) ^ ((2 * c) & 7) ^ (rb & 7);
            offB[nj][ks] = AU16 + (lo + 8 * (rb + 32 * c)) * 8;
        }

    // ---- staging source pointers (inverse-permuted global addrs) ----
    const u16* pA[2];
    int dA[2];
#pragma unroll
    for (int j = 0; j < MI / 2; j++) {
        const int i  = (MI == 4) ? (wave * 128 + j * 64 + lane) : (wave * 64 + lane);
        const int h  = i >> 3;
        const int rb = h & (RA / 8 - 1);
        const int c  = (MI == 4) ? (h >> 5) : (h >> 4);
        const int r  = rb * 8 + ((lane & 7) ^ ((2 * c) & 7) ^ (rb & 7));
        pA[j] = X + (size_t)(m0 + r) * CC + c * 8;
        dA[j] = (i - lane) * 8;                    // wave-uniform dest base
    }
    const u16* pB[2];
    int dB[2];
#pragma unroll
    for (int j = 0; j < 2; j++) {
        const int i  = wave * 128 + j * 64 + lane;
        const int h  = i >> 3;
        const int rb = h & 31;
        const int c  = h >> 5;
        const int r  = rb * 8 + ((lane & 7) ^ ((2 * c) & 7) ^ (rb & 7));
        pB[j] = W + (size_t)(n0 + r) * CC + c * 8;
        dB[j] = AU16 + (i - lane) * 8;
    }

    // ---- prologue: tiles 0,1 -> bufs 0,1 (one-time full drain) ----
#pragma unroll
    for (int pt = 0; pt < 2; pt++) {
        u16* Lb = L + pt * BUFSTR;
#pragma unroll
        for (int j = 0; j < MI / 2; j++) gload16(pA[j] + pt * 32, Lb + dA[j]);
#pragma unroll
        for (int j = 0; j < 2; j++)      gload16(pB[j] + pt * 32, Lb + dB[j]);
    }
    asm volatile("s_waitcnt vmcnt(0)" ::: "memory");
    __builtin_amdgcn_s_barrier();

    bf16x8 a[MI][2], b0[2], b1[2];
    for (int t = 0; t < NTILE; ++t) {
        u16* Lc = L + (t & 3) * BUFSTR;
        u16* Ln = L + ((t + 2) & 3) * BUFSTR;
        const int kt = (t + 2 < NTILE ? t + 2 : NTILE - 1) * 32;  // clip: harmless restage

        // ---------------- P0: read A-frags + B0, stage A(t+2) ----------------
#pragma unroll
        for (int mi = 0; mi < MI; mi++)
#pragma unroll
            for (int ks = 0; ks < 2; ks++)
                a[mi][ks] = *(const bf16x8*)&Lc[offA[mi][ks]];
#pragma unroll
        for (int ks = 0; ks < 2; ks++)
            b0[ks] = *(const bf16x8*)&Lc[offB[0][ks]];
#pragma unroll
        for (int j = 0; j < MI / 2; j++) gload16(pA[j] + kt, Ln + dA[j]);
        __builtin_amdgcn_sched_barrier(0);
        if constexpr (MI == 4) asm volatile("s_waitcnt vmcnt(4)" ::: "memory");
        else                   asm volatile("s_waitcnt vmcnt(3)" ::: "memory");
        __builtin_amdgcn_s_barrier();
        asm volatile("s_waitcnt lgkmcnt(0)" ::: "memory");
        __builtin_amdgcn_sched_barrier(0);
        __builtin_amdgcn_s_setprio(1);
#pragma unroll
        for (int ks = 0; ks < 2; ks++)
#pragma unroll
            for (int mi = 0; mi < MI; mi++)
                acc[mi][0] = __builtin_amdgcn_mfma_f32_32x32x16_bf16(
                    b0[ks], a[mi][ks], acc[mi][0], 0, 0, 0);
        __builtin_amdgcn_s_setprio(0);
        __builtin_amdgcn_sched_barrier(0);
        __builtin_amdgcn_s_barrier();

        // ---------------- P1: read B1, stage B(t+2) ----------------
#pragma unroll
        for (int ks = 0; ks < 2; ks++)
            b1[ks] = *(const bf16x8*)&Lc[offB[1][ks]];
#pragma unroll
        for (int j = 0; j < 2; j++) gload16(pB[j] + kt, Ln + dB[j]);
        __builtin_amdgcn_sched_barrier(0);
        if constexpr (MI == 4) asm volatile("s_waitcnt vmcnt(4)" ::: "memory");
        else                   asm volatile("s_waitcnt vmcnt(3)" ::: "memory");
        __builtin_amdgcn_s_barrier();
        asm volatile("s_waitcnt lgkmcnt(0)" ::: "memory");
        __builtin_amdgcn_sched_barrier(0);
        __builtin_amdgcn_s_setprio(1);
#pragma unroll
        for (int ks = 0; ks < 2; ks++)
#pragma unroll
            for (int mi = 0; mi < MI; mi++)
                acc[mi][1] = __builtin_amdgcn_mfma_f32_32x32x16_bf16(
                    b1[ks], a[mi][ks], acc[mi][1], 0, 0, 0);
        __builtin_amdgcn_s_setprio(0);
        __builtin_amdgcn_sched_barrier(0);
        __builtin_amdgcn_s_barrier();
    }
}

// ============ fused QKV: M=8192, N=3*1024, BM=256, grid (32, 12) ============
__global__ __launch_bounds__(512, 2) void gemm_qkv(
    const u16* __restrict__ X,
    const u16* __restrict__ Wq, const u16* __restrict__ Wk, const u16* __restrict__ Wv,
    const u16* __restrict__ bq, const u16* __restrict__ bk, const u16* __restrict__ bv,
    u16* __restrict__ Q, u16* __restrict__ K, u16* __restrict__ VT)
{
    __shared__ __align__(16) u16 L[4 * 16384];   // 128 KB: 4-deep ring

    const int tid  = threadIdx.x;
    const int wave = tid >> 6;
    const int lane = tid & 63;
    const int l32  = lane & 31;
    const int hv   = lane >> 5;
    const int m0   = blockIdx.x * 256;
    const int by   = blockIdx.y;
    const int z    = by >> 2;
    const int n0   = (by & 3) * 256;

    const u16* W    = (z == 0) ? Wq : (z == 1) ? Wk : Wv;
    const u16* bias = (z == 0) ? bq : (z == 1) ? bk : bv;

    f32x16 acc[4][2];
#pragma unroll
    for (int i = 0; i < 4; i++)
#pragma unroll
        for (int j = 0; j < 2; j++) acc[i][j] = (f32x16)0.0f;

    gemm8p<4>(X, W, &L[0], acc, m0, n0, wave, lane);

    const float scale = (z == 0) ? 0.18033688f : 1.0f;  // 0.125*log2(e) into Q
    u16* outp = (z == 0) ? Q : (z == 1) ? K : VT;
    const int wm = (wave >> 2) * 128;
    const int wn = (wave & 3) * 64;

#pragma unroll
    for (int j = 0; j < 2; j++) {
#pragma unroll
        for (int rq = 0; rq < 4; rq++) {
            const int nn = n0 + wn + j * 32 + rq * 8 + hv * 4;  // 4 consecutive n (in z)
            union { uint2 u; u16 us[4]; } braw;
            braw.u = *(const uint2*)&bias[nn];
            const int hh = nn >> 6, d0 = nn & 63;
#pragma unroll
            for (int i = 0; i < 4; i++) {
                const int m = m0 + wm + i * 32 + l32;
                const int bb = m >> 11, t = m & (TT - 1);
                float v0 = (acc[i][j][rq * 4 + 0] + bf2f(braw.us[0])) * scale;
                float v1 = (acc[i][j][rq * 4 + 1] + bf2f(braw.us[1])) * scale;
                float v2 = (acc[i][j][rq * 4 + 2] + bf2f(braw.us[2])) * scale;
                float v3 = (acc[i][j][rq * 4 + 3] + bf2f(braw.us[3])) * scale;
                if (z < 2) {
                    *(uint2*)&outp[((size_t)(bb * HH + hh) * TT + t) * DD + d0] =
                        pack4(v0, v1, v2, v3);
                } else {
                    const size_t base = (size_t)(bb * HH + hh) * DD * TT + t;
                    outp[base + (size_t)(d0 + 0) * TT] = f2bf(v0);
                    outp[base + (size_t)(d0 + 1) * TT] = f2bf(v1);
                    outp[base + (size_t)(d0 + 2) * TT] = f2bf(v2);
                    outp[base + (size_t)(d0 + 3) * TT] = f2bf(v3);
                }
            }
        }
    }
}

// ============ proj: M=8192, N=1024, BM=128, grid (64, 4) = 256 blocks ============
__global__ __launch_bounds__(512, 2) void gemm_proj(
    const u16* __restrict__ X, const u16* __restrict__ W,
    const u16* __restrict__ bias, void* __restrict__ out,
    const u16* __restrict__ xprobe)
{
    __shared__ __align__(16) u16 L[4 * 12288];   // 96 KB
    __shared__ int sh[8];

    const int isbf = detect_bf16_512(xprobe, sh);

    const int tid  = threadIdx.x;
    const int wave = tid >> 6;
    const int lane = tid & 63;
    const int l32  = lane & 31;
    const int hv   = lane >> 5;
    const int m0   = blockIdx.x * 128;
    const int n0   = blockIdx.y * 256;

    f32x16 acc[2][2];
#pragma unroll
    for (int i = 0; i < 2; i++)
#pragma unroll
        for (int j = 0; j < 2; j++) acc[i][j] = (f32x16)0.0f;

    gemm8p<2>(X, W, &L[0], acc, m0, n0, wave, lane);

    const int wm = (wave >> 2) * 64;
    const int wn = (wave & 3) * 64;

#pragma unroll
    for (int j = 0; j < 2; j++) {
#pragma unroll
        for (int rq = 0; rq < 4; rq++) {
            const int nn = n0 + wn + j * 32 + rq * 8 + hv * 4;
            union { uint2 u; u16 us[4]; } braw;
            braw.u = *(const uint2*)&bias[nn];
#pragma unroll
            for (int i = 0; i < 2; i++) {
                const int m = m0 + wm + i * 32 + l32;
                float v0 = acc[i][j][rq * 4 + 0] + bf2f(braw.us[0]);
                float v1 = acc[i][j][rq * 4 + 1] + bf2f(braw.us[1]);
                float v2 = acc[i][j][rq * 4 + 2] + bf2f(braw.us[2]);
                float v3 = acc[i][j][rq * 4 + 3] + bf2f(braw.us[3]);
                if (isbf) {
                    *(uint2*)&((u16*)out)[(size_t)m * CC + nn] = pack4(v0, v1, v2, v3);
                } else {
                    float4 f; f.x = v0; f.y = v1; f.z = v2; f.w = v3;
                    *(float4*)&((float*)out)[(size_t)m * CC + nn] = f;
                }
            }
        }
    }
}

// ========== flash attention: Q-tile 128, kv-tile 64, 16x16x32, S^T form ======
// LDS 35.3 KB -> 4 blocks/CU. Q fragments loaded directly from global.
__global__ __launch_bounds__(256, 4) void attn_kernel(
    const u16* __restrict__ Qg, const u16* __restrict__ Kg,
    const u16* __restrict__ VTg, u16* __restrict__ Yg)
{
    __shared__ __align__(16) u16 Ks[64 * 64];     // 8 KB
    __shared__ __align__(16) u16 VTs[64 * 64];    // 8 KB
    __shared__ __align__(16) u16 Ps[128 * PSTR];  // 18 KB
    __shared__ float ls[128];

    const int tid  = threadIdx.x;
    const int wave = tid >> 6;
    const int lane = tid & 63;
    const int quad = lane >> 4;
    const int l16  = lane & 15;
    const int bh    = blockIdx.x;                   // XCD = bh%8: K/V L2-pinned
    const int qtile = (TT / 128 - 1) - blockIdx.y;  // heavy tiles first
    const int h = bh & (HH - 1);
    const int b = bh >> 4;
    const int q0 = qtile * 128;

    // Q fragments direct from global (A-op 16x16x32: m=l16, k=quad*8 + ks*32)
    bf16x8 qf[2][2];
#pragma unroll
    for (int g = 0; g < 2; g++)
#pragma unroll
        for (int ks = 0; ks < 2; ks++)
            qf[g][ks] = *(const bf16x8*)&Qg[((size_t)bh * TT + q0 + wave * 32 +
                                             g * 16 + l16) * DD + ks * 32 + quad * 8];

    // K/V staging pointers: 16 rows/wave, XOR-swizzled 16B chunks
    const int sch = (lane & 7) ^ (lane >> 3);
    const u16* kp[2];
    const u16* vp[2];
#pragma unroll
    for (int c = 0; c < 2; c++) {
        const int srow = wave * 16 + c * 8 + (lane >> 3);
        kp[c] = Kg + (size_t)bh * TT * DD + (size_t)srow * DD + sch * 8;
        vp[c] = VTg + (size_t)bh * DD * TT + (size_t)srow * TT + sch * 8;
    }

    f32x4 o_acc[2][4];
#pragma unroll
    for (int g = 0; g < 2; g++)
#pragma unroll
        for (int jt = 0; jt < 4; jt++) o_acc[g][jt] = (f32x4)0.0f;
    float lsum[2] = {0.0f, 0.0f};

    const int ntiles = 2 * qtile;

    for (int kv = 0; kv < ntiles + 2; kv++) {
        const bool masked = (kv >= ntiles);
        __syncthreads();
#pragma unroll
        for (int c = 0; c < 2; c++) {
            gload16(kp[c], &Ks[wave * 1024 + c * 512]);
            gload16(vp[c], &VTs[wave * 1024 + c * 512]);
            kp[c] += 64 * DD;
            vp[c] += 64;
        }
        __syncthreads();

        // S^T = K Q^T
        f32x4 st[2][4];
#pragma unroll
        for (int g = 0; g < 2; g++)
#pragma unroll
            for (int j = 0; j < 4; j++) st[g][j] = (f32x4)0.0f;
#pragma unroll
        for (int ks = 0; ks < 2; ks++) {
            const int rsw = ((ks * 4 + quad) ^ (l16 & 7)) * 8;
#pragma unroll
            for (int j = 0; j < 4; j++) {
                bf16x8 kf = *(const bf16x8*)&Ks[(j * 16 + l16) * 64 + rsw];
#pragma unroll
                for (int g = 0; g < 2; g++)
                    st[g][j] = __builtin_amdgcn_mfma_f32_16x16x32_bf16(
                        kf, qf[g][ks], st[g][j], 0, 0, 0);
            }
        }

        // p = 2^s (scale folded into Q); mask only in last two tiles
#pragma unroll
        for (int g = 0; g < 2; g++) {
            u16* psrow = &Ps[(wave * 32 + g * 16 + l16) * PSTR];
            const int qrow = q0 + wave * 32 + g * 16 + l16;
            float lp = 0.0f;
#pragma unroll
            for (int j = 0; j < 4; j++) {
                float e0 = fast_exp2(st[g][j][0]);
                float e1 = fast_exp2(st[g][j][1]);
                float e2 = fast_exp2(st[g][j][2]);
                float e3 = fast_exp2(st[g][j][3]);
                if (masked) {
                    const int kc = kv * 64 + j * 16 + quad * 4;
                    if (kc + 0 > qrow) e0 = 0.0f;
                    if (kc + 1 > qrow) e1 = 0.0f;
                    if (kc + 2 > qrow) e2 = 0.0f;
                    if (kc + 3 > qrow) e3 = 0.0f;
                }
                lp += (e0 + e1) + (e2 + e3);
                uint2 pk;
                pk.x = pack_bf16(__float_as_uint(e0) + 0x8000u,
                                 __float_as_uint(e1) + 0x8000u);
                pk.y = pack_bf16(__float_as_uint(e2) + 0x8000u,
                                 __float_as_uint(e3) + 0x8000u);
                *(uint2*)&psrow[j * 16 + quad * 4] = pk;
            }
            lsum[g] += lp;
        }

        // O += P V, V-fragments hoisted per ks
#pragma unroll
        for (int ks = 0; ks < 2; ks++) {
            const int rsw = ((ks * 4 + quad) ^ (l16 & 7)) * 8;
            bf16x8 vfk[4];
#pragma unroll
            for (int jt = 0; jt < 4; jt++)
                vfk[jt] = *(const bf16x8*)&VTs[(jt * 16 + l16) * 64 + rsw];
#pragma unroll
            for (int g = 0; g < 2; g++) {
                bf16x8 pf = *(const bf16x8*)&Ps[(wave * 32 + g * 16 + l16) * PSTR +
                                                ks * 32 + quad * 8];
#pragma unroll
                for (int jt = 0; jt < 4; jt++)
                    o_acc[g][jt] = __builtin_amdgcn_mfma_f32_16x16x32_bf16(
                        pf, vfk[jt], o_acc[g][jt], 0, 0, 0);
            }
        }
    }

#pragma unroll
    for (int g = 0; g < 2; g++) {
        lsum[g] += __shfl_xor(lsum[g], 16, 64);
        lsum[g] += __shfl_xor(lsum[g], 32, 64);
        ls[wave * 32 + g * 16 + l16] = lsum[g];
    }

#pragma unroll
    for (int g = 0; g < 2; g++) {
        float linv[4];
#pragma unroll
        for (int r = 0; r < 4; r++)
            linv[r] = 1.0f / fmaxf(ls[wave * 32 + g * 16 + quad * 4 + r], 1e-20f);
#pragma unroll
        for (int jt = 0; jt < 4; jt++) {
#pragma unroll
            for (int r = 0; r < 4; r++) {
                const int t = q0 + wave * 32 + g * 16 + quad * 4 + r;
                const int c = h * DD + jt * 16 + l16;
                Yg[((size_t)b * TT + t) * CC + c] = f2bf(o_acc[g][jt][r] * linv[r]);
            }
        }
    }
}

extern "C" void kernel_launch(void* const* d_in, const int* in_sizes, int n_in,
                              void* d_out, int out_size, void* d_ws, size_t ws_size,
                              hipStream_t stream) {
    u16* w = (u16*)d_ws;
    size_t off = 0;
    const size_t NX = (size_t)BB * TT * CC;
    const size_t NW = (size_t)CC * CC;
    const size_t NB = CC;
    const size_t per = (size_t)BB * HH * TT * DD;

    u16* xb  = w + off; off += NX;
    u16* Wqb = w + off; off += NW;
    u16* Wkb = w + off; off += NW;
    u16* Wvb = w + off; off += NW;
    u16* Wpb = w + off; off += NW;
    u16* bqb = w + off; off += NB;
    u16* bkb = w + off; off += NB;
    u16* bvb = w + off; off += NB;
    u16* bpb = w + off; off += NB;
    u16* Q   = w + off; off += per;
    u16* K   = w + off; off += per;
    u16* VT  = w + off; off += per;
    u16* Y   = w + off; off += per;

    CastArgs ca;
    const int srcmap[9] = {0, 1, 3, 5, 7, 2, 4, 6, 8};
    u16* dsts[9] = {xb, Wqb, Wkb, Wvb, Wpb, bqb, bkb, bvb, bpb};
    int ns[9] = {(int)NX, (int)NW, (int)NW, (int)NW, (int)NW,
                 (int)NB, (int)NB, (int)NB, (int)NB};
    int acc_blk = 0;
    for (int i = 0; i < 9; i++) {
        ca.src[i] = d_in[srcmap[i]];
        ca.dst[i] = dsts[i];
        ca.n[i]   = ns[i];
        ca.blk_start[i] = acc_blk;
        acc_blk += (ns[i] + 2047) / 2048;
    }
    ca.blk_start[9] = acc_blk;
    cast_all<<<acc_blk, 256, 0, stream>>>(ca, (const u16*)d_in[0]);

    gemm_qkv<<<dim3(32, 12), 512, 0, stream>>>(xb, Wqb, Wkb, Wvb,
                                               bqb, bkb, bvb, Q, K, VT);
    attn_kernel<<<dim3(BB * HH, TT / 128), 256, 0, stream>>>(Q, K, VT, Y);
    gemm_proj<<<dim3(64, 4), 512, 0, stream>>>(Y, Wpb, bpb, d_out,
                                               (const u16*)d_in[0]);
}

// Round 2
// 304.761 us; speedup vs baseline: 1.0169x; 1.0169x over previous
//
#include <hip/hip_runtime.h>
#include <hip/hip_bf16.h>

#define BB 4
#define TT 2048
#define CC 1024
#define HH 16
#define DD 64
#define PSTR 72   // Ps row stride in u16 (144B = 9*16B: aligned, 2-way-free banks)

typedef unsigned short u16;
typedef __attribute__((ext_vector_type(8))) short bf16x8;
typedef __attribute__((ext_vector_type(4))) float f32x4;
typedef __attribute__((ext_vector_type(16))) float f32x16;

__device__ __forceinline__ float bf2f(u16 v) {
    union { unsigned u; float f; } c; c.u = ((unsigned)v) << 16; return c.f;
}
__device__ __forceinline__ u16 f2bf(float f) {
    union { float f; unsigned u; } c; c.f = f;
    unsigned u = c.u + 0x7fffu + ((c.u >> 16) & 1u);
    return (u16)(u >> 16);
}
__device__ __forceinline__ float fast_exp2(float x) {
    float r;
    asm volatile("v_exp_f32 %0, %1\n\ts_nop 1" : "=v"(r) : "v"(x));
    return r;
}
__device__ __forceinline__ unsigned pack_bf16(unsigned b0, unsigned b1) {
    unsigned d;
    asm("v_perm_b32 %0, %1, %2, %3" : "=v"(d) : "v"(b1), "v"(b0), "v"(0x07060302u));
    return d;
}
__device__ __forceinline__ uint2 pack4(float v0, float v1, float v2, float v3) {
    uint2 pk;
    pk.x = pack_bf16(__float_as_uint(v0) + 0x8000u, __float_as_uint(v1) + 0x8000u);
    pk.y = pack_bf16(__float_as_uint(v2) + 0x8000u, __float_as_uint(v3) + 0x8000u);
    return pk;
}
__device__ __forceinline__ void gload16(const u16* g, u16* l) {
    __builtin_amdgcn_global_load_lds(
        (const __attribute__((address_space(1))) void*)g,
        (__attribute__((address_space(3))) void*)l, 16, 0, 0);
}

// inline dtype detect (256-thread blocks): even u16s of x; bf16 ~248 hits, fp32 ~15
__device__ __forceinline__ int detect_bf16(const u16* __restrict__ xprobe, int* sh) {
    const int t = threadIdx.x;
    u16 hh = xprobe[2 * t];
    int e = (hh >> 7) & 0xFF;
    unsigned long long m = __ballot(e >= 118 && e <= 132);
    if ((t & 63) == 0) sh[t >> 6] = __popcll(m);
    __syncthreads();
    return (sh[0] + sh[1] + sh[2] + sh[3]) >= 128;
}

// ---- fused canonicalize (detect inlined) ----
struct CastArgs {
    const void* src[9];
    u16* dst[9];
    int blk_start[10];
    int n[9];
};
__global__ __launch_bounds__(256) void cast_all(CastArgs a, const u16* __restrict__ xprobe) {
    __shared__ int sh[4];
    const int isbf = detect_bf16(xprobe, sh);
    int b = blockIdx.x;
    int s = 0;
    while (s < 8 && b >= a.blk_start[s + 1]) s++;
    int i0 = (b - a.blk_start[s]) * 2048 + threadIdx.x * 8;
    if (i0 + 8 > a.n[s]) return;
    if (isbf) {
        *(uint4*)&a.dst[s][i0] = *(const uint4*)&((const u16*)a.src[s])[i0];
    } else {
        const float* sp = (const float*)a.src[s];
        u16 tmp[8];
#pragma unroll
        for (int j = 0; j < 8; j++) tmp[j] = f2bf(sp[i0 + j]);
        *(uint4*)&a.dst[s][i0] = *(uint4*)tmp;
    }
}

// ============================================================================
// GEMM core v3: ring-3 counted-vmcnt pipeline.
//   BM=128, BN=256, BK=32, 256 thr (4 waves, 1M x 4N), per-wave out 128x64.
//   LDS: 3 bufs x (A 8KB + B 16KB) = 72 KB -> 2 blocks/CU (TLP for stalls).
// Per tile t (ONE barrier, ONE counted wait):
//   1) 12x ds_read_b128 frags of tile t        (buf t%3)
//   2) 6x global_load_lds staging tile t+2     (buf (t+2)%3)
//   3) s_waitcnt vmcnt(6) lgkmcnt(0)   [retires tile t+1 fully; own reads done]
//   4) s_barrier                       [t+1 globally visible; t's buf now dead]
//   5) setprio(1); 16x mfma_32x32x16; setprio(0)
// Correctness: tile t visible at t-1's wait+barrier; stage into buf (t-1)%3 is
// issued only after barrier(t-1), and reads of t-1 drained (lgkm) before it.
// LDS cell layout (16B cells): cell(r,c) at lo + 8*(rb + R/8*c),
//   lo=(r&7)^((2c)&7)^(rb&7), rb=r>>3  -> 0 bank conflicts (measured r1).
// Staging keeps gload_lds dest linear; global src carries inverse permutation.
// ============================================================================
__device__ __forceinline__ void gemm_pipe(
    const u16* __restrict__ X, const u16* __restrict__ W,
    u16* L, f32x16 (&acc)[4][2], int m0, int n0, int wave, int lane)
{
    constexpr int AU16   = 4096;        // A bytes/2 per buf: 128*32
    constexpr int BUFSTR = 12288;       // + B 256*32
    constexpr int NT     = CC / 32;     // 32 K-tiles

    const int l32 = lane & 31;
    const int hv  = lane >> 5;
    const int wn  = wave * 64;

    // ---- LDS read offsets (u16), fixed across tiles ----
    int offA[4][2], offB[2][2];
#pragma unroll
    for (int mi = 0; mi < 4; mi++)
#pragma unroll
        for (int ks = 0; ks < 2; ks++) {
            const int r  = mi * 32 + l32;
            const int c  = ks * 2 + hv;
            const int rb = r >> 3;
            const int lo = (r & 7) ^ ((2 * c) & 7) ^ (rb & 7);
            offA[mi][ks] = (lo + 8 * (rb + 16 * c)) * 8;
        }
#pragma unroll
    for (int nj = 0; nj < 2; nj++)
#pragma unroll
        for (int ks = 0; ks < 2; ks++) {
            const int r  = wn + nj * 32 + l32;
            const int c  = ks * 2 + hv;
            const int rb = r >> 3;
            const int lo = (r & 7) ^ ((2 * c) & 7) ^ (rb & 7);
            offB[nj][ks] = AU16 + (lo + 8 * (rb + 32 * c)) * 8;
        }

    // ---- staging source pointers (inverse-permuted global addrs) ----
    const u16* pA[2];
    int dA[2];
#pragma unroll
    for (int j = 0; j < 2; j++) {
        const int i  = wave * 128 + j * 64 + lane;
        const int h  = i >> 3;
        const int rb = h & 15;
        const int c  = h >> 4;
        const int r  = rb * 8 + ((lane & 7) ^ ((2 * c) & 7) ^ (rb & 7));
        pA[j] = X + (size_t)(m0 + r) * CC + c * 8;
        dA[j] = (wave * 128 + j * 64) * 8;          // wave-uniform dest base
    }
    const u16* pB[4];
    int dB[4];
#pragma unroll
    for (int j = 0; j < 4; j++) {
        const int i  = wave * 256 + j * 64 + lane;
        const int h  = i >> 3;
        const int rb = h & 31;
        const int c  = h >> 5;
        const int r  = rb * 8 + ((lane & 7) ^ ((2 * c) & 7) ^ (rb & 7));
        pB[j] = W + (size_t)(n0 + r) * CC + c * 8;
        dB[j] = AU16 + (wave * 256 + j * 64) * 8;
    }

    // ---- prologue: stage tiles 0,1 -> bufs 0,1; full drain once ----
#pragma unroll
    for (int pt = 0; pt < 2; pt++) {
        u16* Lb = L + pt * BUFSTR;
#pragma unroll
        for (int j = 0; j < 2; j++) gload16(pA[j] + pt * 32, Lb + dA[j]);
#pragma unroll
        for (int j = 0; j < 4; j++) gload16(pB[j] + pt * 32, Lb + dB[j]);
    }
    asm volatile("s_waitcnt vmcnt(0)" ::: "memory");
    __builtin_amdgcn_s_barrier();

    int cur = 0, stg = 2;
    for (int t = 0; t < NT; ++t) {
        u16* Lc = L + cur * BUFSTR;
        u16* Ls = L + stg * BUFSTR;
        const int kt = (t + 2 < NT ? t + 2 : NT - 1) * 32;  // clip: harmless restage

        // 1) fragment reads of tile t
        bf16x8 a[4][2], b[2][2];
#pragma unroll
        for (int mi = 0; mi < 4; mi++)
#pragma unroll
            for (int ks = 0; ks < 2; ks++)
                a[mi][ks] = *(const bf16x8*)&Lc[offA[mi][ks]];
#pragma unroll
        for (int nj = 0; nj < 2; nj++)
#pragma unroll
            for (int ks = 0; ks < 2; ks++)
                b[nj][ks] = *(const bf16x8*)&Lc[offB[nj][ks]];

        // 2) stage tile t+2
#pragma unroll
        for (int j = 0; j < 2; j++) gload16(pA[j] + kt, Ls + dA[j]);
#pragma unroll
        for (int j = 0; j < 4; j++) gload16(pB[j] + kt, Ls + dB[j]);
        __builtin_amdgcn_sched_barrier(0);

        // 3) retire tile t+1 (6 loads in flight = tile t+2); drain own reads
        asm volatile("s_waitcnt vmcnt(6) lgkmcnt(0)" ::: "memory");
        // 4) single barrier per tile
        __builtin_amdgcn_s_barrier();

        // 5) MFMA cluster
        __builtin_amdgcn_s_setprio(1);
#pragma unroll
        for (int ks = 0; ks < 2; ks++)
#pragma unroll
            for (int mi = 0; mi < 4; mi++)
#pragma unroll
                for (int nj = 0; nj < 2; nj++)
                    acc[mi][nj] = __builtin_amdgcn_mfma_f32_32x32x16_bf16(
                        b[nj][ks], a[mi][ks], acc[mi][nj], 0, 0, 0);   // C^T form
        __builtin_amdgcn_s_setprio(0);

        cur = (cur == 2) ? 0 : cur + 1;
        stg = (stg == 2) ? 0 : stg + 1;
    }
}

// ============ fused QKV: M=8192, N=3*1024, BM=128, grid (64, 12) ============
__global__ __launch_bounds__(256, 2) void gemm_qkv(
    const u16* __restrict__ X,
    const u16* __restrict__ Wq, const u16* __restrict__ Wk, const u16* __restrict__ Wv,
    const u16* __restrict__ bq, const u16* __restrict__ bk, const u16* __restrict__ bv,
    u16* __restrict__ Q, u16* __restrict__ K, u16* __restrict__ VT)
{
    __shared__ __align__(16) u16 L[3 * 12288];   // 72 KB ring-3

    const int tid  = threadIdx.x;
    const int wave = tid >> 6;
    const int lane = tid & 63;
    const int l32  = lane & 31;
    const int hv   = lane >> 5;
    const int m0   = blockIdx.x * 128;
    const int by   = blockIdx.y;
    const int z    = by >> 2;
    const int n0   = (by & 3) * 256;

    const u16* W    = (z == 0) ? Wq : (z == 1) ? Wk : Wv;
    const u16* bias = (z == 0) ? bq : (z == 1) ? bk : bv;

    f32x16 acc[4][2];
#pragma unroll
    for (int i = 0; i < 4; i++)
#pragma unroll
        for (int j = 0; j < 2; j++) acc[i][j] = (f32x16)0.0f;

    gemm_pipe(X, W, &L[0], acc, m0, n0, wave, lane);

    const float scale = (z == 0) ? 0.18033688f : 1.0f;  // 0.125*log2(e) into Q
    u16* outp = (z == 0) ? Q : (z == 1) ? K : VT;

#pragma unroll
    for (int j = 0; j < 2; j++) {
#pragma unroll
        for (int rq = 0; rq < 4; rq++) {
            const int nn = n0 + wave * 64 + j * 32 + rq * 8 + hv * 4;  // 4 consecutive n
            union { uint2 u; u16 us[4]; } braw;
            braw.u = *(const uint2*)&bias[nn];
            const int hh = nn >> 6, d0 = nn & 63;
#pragma unroll
            for (int i = 0; i < 4; i++) {
                const int m = m0 + i * 32 + l32;
                const int bb = m >> 11, t = m & (TT - 1);
                float v0 = (acc[i][j][rq * 4 + 0] + bf2f(braw.us[0])) * scale;
                float v1 = (acc[i][j][rq * 4 + 1] + bf2f(braw.us[1])) * scale;
                float v2 = (acc[i][j][rq * 4 + 2] + bf2f(braw.us[2])) * scale;
                float v3 = (acc[i][j][rq * 4 + 3] + bf2f(braw.us[3])) * scale;
                if (z < 2) {
                    *(uint2*)&outp[((size_t)(bb * HH + hh) * TT + t) * DD + d0] =
                        pack4(v0, v1, v2, v3);
                } else {
                    const size_t base = (size_t)(bb * HH + hh) * DD * TT + t;
                    outp[base + (size_t)(d0 + 0) * TT] = f2bf(v0);
                    outp[base + (size_t)(d0 + 1) * TT] = f2bf(v1);
                    outp[base + (size_t)(d0 + 2) * TT] = f2bf(v2);
                    outp[base + (size_t)(d0 + 3) * TT] = f2bf(v3);
                }
            }
        }
    }
}

// ============ proj: M=8192, N=1024, BM=128, grid (64, 4) = 256 blocks ============
__global__ __launch_bounds__(256, 2) void gemm_proj(
    const u16* __restrict__ X, const u16* __restrict__ W,
    const u16* __restrict__ bias, void* __restrict__ out,
    const u16* __restrict__ xprobe)
{
    __shared__ __align__(16) u16 L[3 * 12288];   // 72 KB ring-3
    __shared__ int sh[4];

    const int isbf = detect_bf16(xprobe, sh);

    const int tid  = threadIdx.x;
    const int wave = tid >> 6;
    const int lane = tid & 63;
    const int l32  = lane & 31;
    const int hv   = lane >> 5;
    const int m0   = blockIdx.x * 128;
    const int n0   = blockIdx.y * 256;

    f32x16 acc[4][2];
#pragma unroll
    for (int i = 0; i < 4; i++)
#pragma unroll
        for (int j = 0; j < 2; j++) acc[i][j] = (f32x16)0.0f;

    gemm_pipe(X, W, &L[0], acc, m0, n0, wave, lane);

#pragma unroll
    for (int j = 0; j < 2; j++) {
#pragma unroll
        for (int rq = 0; rq < 4; rq++) {
            const int nn = n0 + wave * 64 + j * 32 + rq * 8 + hv * 4;
            union { uint2 u; u16 us[4]; } braw;
            braw.u = *(const uint2*)&bias[nn];
#pragma unroll
            for (int i = 0; i < 4; i++) {
                const int m = m0 + i * 32 + l32;
                float v0 = acc[i][j][rq * 4 + 0] + bf2f(braw.us[0]);
                float v1 = acc[i][j][rq * 4 + 1] + bf2f(braw.us[1]);
                float v2 = acc[i][j][rq * 4 + 2] + bf2f(braw.us[2]);
                float v3 = acc[i][j][rq * 4 + 3] + bf2f(braw.us[3]);
                if (isbf) {
                    *(uint2*)&((u16*)out)[(size_t)m * CC + nn] = pack4(v0, v1, v2, v3);
                } else {
                    float4 f; f.x = v0; f.y = v1; f.z = v2; f.w = v3;
                    *(float4*)&((float*)out)[(size_t)m * CC + nn] = f;
                }
            }
        }
    }
}

// ========== flash attention: Q-tile 128, kv-tile 64, 16x16x32, S^T form ======
// LDS 35.3 KB -> 4 blocks/CU. Q fragments loaded directly from global.
__global__ __launch_bounds__(256, 4) void attn_kernel(
    const u16* __restrict__ Qg, const u16* __restrict__ Kg,
    const u16* __restrict__ VTg, u16* __restrict__ Yg)
{
    __shared__ __align__(16) u16 Ks[64 * 64];     // 8 KB
    __shared__ __align__(16) u16 VTs[64 * 64];    // 8 KB
    __shared__ __align__(16) u16 Ps[128 * PSTR];  // 18 KB
    __shared__ float ls[128];

    const int tid  = threadIdx.x;
    const int wave = tid >> 6;
    const int lane = tid & 63;
    const int quad = lane >> 4;
    const int l16  = lane & 15;
    const int bh    = blockIdx.x;                   // XCD = bh%8: K/V L2-pinned
    const int qtile = (TT / 128 - 1) - blockIdx.y;  // heavy tiles first
    const int h = bh & (HH - 1);
    const int b = bh >> 4;
    const int q0 = qtile * 128;

    // Q fragments direct from global (A-op 16x16x32: m=l16, k=quad*8 + ks*32)
    bf16x8 qf[2][2];
#pragma unroll
    for (int g = 0; g < 2; g++)
#pragma unroll
        for (int ks = 0; ks < 2; ks++)
            qf[g][ks] = *(const bf16x8*)&Qg[((size_t)bh * TT + q0 + wave * 32 +
                                             g * 16 + l16) * DD + ks * 32 + quad * 8];

    // K/V staging pointers: 16 rows/wave, XOR-swizzled 16B chunks
    const int sch = (lane & 7) ^ (lane >> 3);
    const u16* kp[2];
    const u16* vp[2];
#pragma unroll
    for (int c = 0; c < 2; c++) {
        const int srow = wave * 16 + c * 8 + (lane >> 3);
        kp[c] = Kg + (size_t)bh * TT * DD + (size_t)srow * DD + sch * 8;
        vp[c] = VTg + (size_t)bh * DD * TT + (size_t)srow * TT + sch * 8;
    }

    f32x4 o_acc[2][4];
#pragma unroll
    for (int g = 0; g < 2; g++)
#pragma unroll
        for (int jt = 0; jt < 4; jt++) o_acc[g][jt] = (f32x4)0.0f;
    float lsum[2] = {0.0f, 0.0f};

    const int ntiles = 2 * qtile;

    for (int kv = 0; kv < ntiles + 2; kv++) {
        const bool masked = (kv >= ntiles);
        __syncthreads();
#pragma unroll
        for (int c = 0; c < 2; c++) {
            gload16(kp[c], &Ks[wave * 1024 + c * 512]);
            gload16(vp[c], &VTs[wave * 1024 + c * 512]);
            kp[c] += 64 * DD;
            vp[c] += 64;
        }
        __syncthreads();

        // S^T = K Q^T
        f32x4 st[2][4];
#pragma unroll
        for (int g = 0; g < 2; g++)
#pragma unroll
            for (int j = 0; j < 4; j++) st[g][j] = (f32x4)0.0f;
#pragma unroll
        for (int ks = 0; ks < 2; ks++) {
            const int rsw = ((ks * 4 + quad) ^ (l16 & 7)) * 8;
#pragma unroll
            for (int j = 0; j < 4; j++) {
                bf16x8 kf = *(const bf16x8*)&Ks[(j * 16 + l16) * 64 + rsw];
#pragma unroll
                for (int g = 0; g < 2; g++)
                    st[g][j] = __builtin_amdgcn_mfma_f32_16x16x32_bf16(
                        kf, qf[g][ks], st[g][j], 0, 0, 0);
            }
        }

        // p = 2^s (scale folded into Q); mask only in last two tiles
#pragma unroll
        for (int g = 0; g < 2; g++) {
            u16* psrow = &Ps[(wave * 32 + g * 16 + l16) * PSTR];
            const int qrow = q0 + wave * 32 + g * 16 + l16;
            float lp = 0.0f;
#pragma unroll
            for (int j = 0; j < 4; j++) {
                float e0 = fast_exp2(st[g][j][0]);
                float e1 = fast_exp2(st[g][j][1]);
                float e2 = fast_exp2(st[g][j][2]);
                float e3 = fast_exp2(st[g][j][3]);
                if (masked) {
                    const int kc = kv * 64 + j * 16 + quad * 4;
                    if (kc + 0 > qrow) e0 = 0.0f;
                    if (kc + 1 > qrow) e1 = 0.0f;
                    if (kc + 2 > qrow) e2 = 0.0f;
                    if (kc + 3 > qrow) e3 = 0.0f;
                }
                lp += (e0 + e1) + (e2 + e3);
                uint2 pk;
                pk.x = pack_bf16(__float_as_uint(e0) + 0x8000u,
                                 __float_as_uint(e1) + 0x8000u);
                pk.y = pack_bf16(__float_as_uint(e2) + 0x8000u,
                                 __float_as_uint(e3) + 0x8000u);
                *(uint2*)&psrow[j * 16 + quad * 4] = pk;
            }
            lsum[g] += lp;
        }

        // O += P V, V-fragments hoisted per ks
#pragma unroll
        for (int ks = 0; ks < 2; ks++) {
            const int rsw = ((ks * 4 + quad) ^ (l16 & 7)) * 8;
            bf16x8 vfk[4];
#pragma unroll
            for (int jt = 0; jt < 4; jt++)
                vfk[jt] = *(const bf16x8*)&VTs[(jt * 16 + l16) * 64 + rsw];
#pragma unroll
            for (int g = 0; g < 2; g++) {
                bf16x8 pf = *(const bf16x8*)&Ps[(wave * 32 + g * 16 + l16) * PSTR +
                                                ks * 32 + quad * 8];
#pragma unroll
                for (int jt = 0; jt < 4; jt++)
                    o_acc[g][jt] = __builtin_amdgcn_mfma_f32_16x16x32_bf16(
                        pf, vfk[jt], o_acc[g][jt], 0, 0, 0);
            }
        }
    }

#pragma unroll
    for (int g = 0; g < 2; g++) {
        lsum[g] += __shfl_xor(lsum[g], 16, 64);
        lsum[g] += __shfl_xor(lsum[g], 32, 64);
        ls[wave * 32 + g * 16 + l16] = lsum[g];
    }

#pragma unroll
    for (int g = 0; g < 2; g++) {
        float linv[4];
#pragma unroll
        for (int r = 0; r < 4; r++)
            linv[r] = 1.0f / fmaxf(ls[wave * 32 + g * 16 + quad * 4 + r], 1e-20f);
#pragma unroll
        for (int jt = 0; jt < 4; jt++) {
#pragma unroll
            for (int r = 0; r < 4; r++) {
                const int t = q0 + wave * 32 + g * 16 + quad * 4 + r;
                const int c = h * DD + jt * 16 + l16;
                Yg[((size_t)b * TT + t) * CC + c] = f2bf(o_acc[g][jt][r] * linv[r]);
            }
        }
    }
}

extern "C" void kernel_launch(void* const* d_in, const int* in_sizes, int n_in,
                              void* d_out, int out_size, void* d_ws, size_t ws_size,
                              hipStream_t stream) {
    u16* w = (u16*)d_ws;
    size_t off = 0;
    const size_t NX = (size_t)BB * TT * CC;
    const size_t NW = (size_t)CC * CC;
    const size_t NB = CC;
    const size_t per = (size_t)BB * HH * TT * DD;

    u16* xb  = w + off; off += NX;
    u16* Wqb = w + off; off += NW;
    u16* Wkb = w + off; off += NW;
    u16* Wvb = w + off; off += NW;
    u16* Wpb = w + off; off += NW;
    u16* bqb = w + off; off += NB;
    u16* bkb = w + off; off += NB;
    u16* bvb = w + off; off += NB;
    u16* bpb = w + off; off += NB;
    u16* Q   = w + off; off += per;
    u16* K   = w + off; off += per;
    u16* VT  = w + off; off += per;
    u16* Y   = w + off; off += per;

    CastArgs ca;
    const int srcmap[9] = {0, 1, 3, 5, 7, 2, 4, 6, 8};
    u16* dsts[9] = {xb, Wqb, Wkb, Wvb, Wpb, bqb, bkb, bvb, bpb};
    int ns[9] = {(int)NX, (int)NW, (int)NW, (int)NW, (int)NW,
                 (int)NB, (int)NB, (int)NB, (int)NB};
    int acc_blk = 0;
    for (int i = 0; i < 9; i++) {
        ca.src[i] = d_in[srcmap[i]];
        ca.dst[i] = dsts[i];
        ca.n[i]   = ns[i];
        ca.blk_start[i] = acc_blk;
        acc_blk += (ns[i] + 2047) / 2048;
    }
    ca.blk_start[9] = acc_blk;
    cast_all<<<acc_blk, 256, 0, stream>>>(ca, (const u16*)d_in[0]);

    gemm_qkv<<<dim3(64, 12), 256, 0, stream>>>(xb, Wqb, Wkb, Wvb,
                                               bqb, bkb, bvb, Q, K, VT);
    attn_kernel<<<dim3(BB * HH, TT / 128), 256, 0, stream>>>(Q, K, VT, Y);
    gemm_proj<<<dim3(64, 4), 256, 0, stream>>>(Y, Wpb, bpb, d_out,
                                               (const u16*)d_in[0]);
}